// Round 13
// baseline (702.773 us; speedup 1.0000x reference)
//
#include <hip/hip_runtime.h>
#include <stdint.h>

#define F 128
#define NREP 8          // cursor/histogram replicas
#define EPT 8           // edges per thread in histogram/bucket
#define PB 1024         // prop block threads
#define NPT 10          // nodes per thread = ceil(10000/1024)
#define LDSN 10240      // LDS node capacity (40,960 B)

typedef float f32x2 __attribute__((ext_vector_type(2)));
typedef float f32x4 __attribute__((ext_vector_type(4)));
typedef _Float16 h2 __attribute__((ext_vector_type(2)));

union H4 { f32x2 f2; _Float16 h[4]; };
union HS { _Float16 h; unsigned short u; };
union HP { uint32_t u; h2 p; };

struct ER8 { int src; uint32_t n2; };   // 8 B: src + fp16 norm duplicated in both halves

// ---- 1. fused: x(fp32)->xh(fp16) + replicated in-degree histogram ----
__global__ void convdeg_kernel(const float* __restrict__ x, _Float16* __restrict__ xh,
                               int total4, const int* __restrict__ col,
                               int* __restrict__ hist, int E, int N) {
    int rep = blockIdx.x & (NREP - 1);
    int i0 = (blockIdx.x * blockDim.x + threadIdx.x) * EPT;
    int* h = hist + (size_t)rep * N;
#pragma unroll
    for (int u = 0; u < EPT; ++u) {
        int e = i0 + u;
        if (e < E) atomicAdd(&h[__builtin_nontemporal_load(&col[e])], 1);
    }
#pragma unroll
    for (int u = 0; u < EPT; ++u) {
        int i = i0 + u;
        if (i < total4) {
            f32x4 v = __builtin_nontemporal_load(&((const f32x4*)x)[i]);
            H4 p;
            p.h[0] = (_Float16)v.x; p.h[1] = (_Float16)v.y;
            p.h[2] = (_Float16)v.z; p.h[3] = (_Float16)v.w;
            ((f32x2*)xh)[i] = p.f2;
        }
    }
}

// ---- 2. node-side: deg-sum + dinv + scan + cursor seed + degree-sorted norder ----
__global__ __launch_bounds__(1024) void nodeproc_kernel(
        const int* __restrict__ hist, float* __restrict__ dinv,
        int* __restrict__ start, int* __restrict__ cursor,
        int* __restrict__ norder, int N) {
    __shared__ int wsum[16];
    __shared__ int carry_s;
    __shared__ int dh[256], db[256];
    int tid = threadIdx.x, lane = tid & 63, wid = tid >> 6;
    if (tid == 0) carry_s = 0;
    if (tid < 256) dh[tid] = 0;
    __syncthreads();
    for (int base = 0; base < N; base += 1024) {
        int i = base + tid;
        int h[NREP];
        int v = 0;
        if (i < N) {
#pragma unroll
            for (int r = 0; r < NREP; ++r) { h[r] = hist[(size_t)r * N + i]; v += h[r]; }
            int d = v < 1 ? 1 : v;
            dinv[i] = rsqrtf((float)d);
        }
        int inc = v;
        for (int off = 1; off < 64; off <<= 1) {
            int t = __shfl_up(inc, off, 64);
            if (lane >= off) inc += t;
        }
        if (lane == 63) wsum[wid] = inc;
        __syncthreads();
        if (wid == 0) {
            int wv = (lane < 16) ? wsum[lane] : 0;
            for (int off = 1; off < 16; off <<= 1) {
                int t = __shfl_up(wv, off, 64);
                if (lane >= off) wv += t;
            }
            if (lane < 16) wsum[lane] = wv;
        }
        __syncthreads();
        int carry = carry_s;
        int woff = (wid > 0) ? wsum[wid - 1] : 0;
        if (i < N) {
            int st = carry + woff + inc - v;
            start[i] = st;
            int run = st;
#pragma unroll
            for (int r = 0; r < NREP; ++r) { cursor[(size_t)r * N + i] = run; run += h[r]; }
        }
        __syncthreads();
        if (tid == 0) carry_s = carry + wsum[15];
        __syncthreads();
    }
    if (tid == 0) start[N] = carry_s;
    __syncthreads();
    // counting sort of nodes by degree -> norder (groups similar degrees so
    // prop waves get near-uniform edge counts per lane)
    for (int v = tid; v < N; v += 1024) {
        int d = start[v + 1] - start[v]; if (d > 255) d = 255;
        atomicAdd(&dh[d], 1);
    }
    __syncthreads();
    if (tid == 0) {
        int run = 0;
        for (int b2 = 0; b2 < 256; ++b2) { db[b2] = run; run += dh[b2]; dh[b2] = 0; }
    }
    __syncthreads();
    for (int v = tid; v < N; v += 1024) {
        int d = start[v + 1] - start[v]; if (d > 255) d = 255;
        int pos = db[d] + atomicAdd(&dh[d], 1);
        norder[pos] = v;
    }
}

// ---- 3. bucket scatter: 8B records {src, dup fp16 norm}, pre-seeded cursors ----
__global__ void bucket_kernel(const int* __restrict__ row, const int* __restrict__ col,
                              const float* __restrict__ dinv,
                              int* __restrict__ cursor, ER8* __restrict__ edges,
                              int E, int N) {
    int rep = blockIdx.x & (NREP - 1);
    int e0 = (blockIdx.x * blockDim.x + threadIdx.x) * EPT;
    int* cur = cursor + (size_t)rep * N;
    int cs[EPT], rs[EPT], pos[EPT];
    float nm[EPT];
#pragma unroll
    for (int u = 0; u < EPT; ++u) {
        int e = e0 + u;
        if (e < E) {
            cs[u] = __builtin_nontemporal_load(&col[e]);
            rs[u] = __builtin_nontemporal_load(&row[e]);
        }
    }
#pragma unroll
    for (int u = 0; u < EPT; ++u) {
        int e = e0 + u;
        if (e < E) {
            nm[u]  = dinv[rs[u]] * dinv[cs[u]];
            pos[u] = atomicAdd(&cur[cs[u]], 1);
        }
    }
#pragma unroll
    for (int u = 0; u < EPT; ++u) {
        int e = e0 + u;
        if (e < E) {
            HS hs; hs.h = (_Float16)nm[u];
            ER8 r8; r8.src = rs[u]; r8.n2 = (uint32_t)hs.u * 0x00010001u;
            edges[pos[u]] = r8;
        }
    }
}

// ---- 4. ALL 8 layers, LDS-resident, feature-sliced ----
// Block b owns feature pair (2b, 2b+1) of ALL nodes in LDS (40 KB).
// Per layer: compute into registers -> barrier -> write back -> barrier.
// upd accumulates in fp32 registers (static NPT unroll); one store at end.
__global__ __launch_bounds__(PB, 4) void prop_kernel(
        const _Float16* __restrict__ xh, const ER8* __restrict__ edges,
        const int* __restrict__ start, const int* __restrict__ norder,
        const float* __restrict__ kv, float* __restrict__ updg,
        int N, int L) {
    __shared__ uint32_t cur[LDSN];       // 2 fp16 per node
    const int s = blockIdx.x;            // feature slice: feats 2s, 2s+1
    const int tid = threadIdx.x;

    int vid[NPT], es[NPT], ec[NPT];
    f32x2 upd[NPT];
    uint32_t newc[NPT];
#pragma unroll
    for (int i = 0; i < NPT; ++i) {
        int r = i * PB + tid;
        int v = -1;
        if (r < N) v = norder[r];
        vid[i] = v;
        es[i] = 0; ec[i] = 0;
        upd[i].x = 0.f; upd[i].y = 0.f;
        if (v >= 0) {
            es[i] = start[v];
            ec[i] = start[v + 1] - es[i];
            cur[v] = *(const uint32_t*)(xh + (size_t)v * F + 2 * s);
        }
    }
    __syncthreads();

    for (int l = 0; l < L; ++l) {
        float tk = tanhf(kv[l]);
#pragma unroll
        for (int i = 0; i < NPT; ++i) {
            int v = vid[i];
            if (v >= 0) {
                float ax = 0.f, ay = 0.f;
                int e = es[i], t = es[i] + ec[i];
                for (; e + 8 <= t; e += 8) {
                    h2 hc = (h2)(_Float16)0.f;
#pragma unroll
                    for (int k = 0; k < 8; ++k) {
                        ER8 r = edges[e + k];
                        HP w; w.u = cur[r.src];
                        HP n; n.u = r.n2;
                        hc += n.p * w.p;          // v_pk_fma_f16
                    }
                    ax += (float)hc[0]; ay += (float)hc[1];
                }
                {
                    h2 hc = (h2)(_Float16)0.f;
                    for (; e < t; ++e) {
                        ER8 r = edges[e];
                        HP w; w.u = cur[r.src];
                        HP n; n.u = r.n2;
                        hc += n.p * w.p;
                    }
                    ax += (float)hc[0]; ay += (float)hc[1];
                }
                HP c0; c0.u = cur[v];
                float nx = (float)c0.p[0] - ax;
                float ny = (float)c0.p[1] - ay;
                HP nc; nc.p[0] = (_Float16)nx; nc.p[1] = (_Float16)ny;
                newc[i] = nc.u;
                upd[i].x += tk * nx;
                upd[i].y += tk * ny;
            }
        }
        __syncthreads();                 // all reads of this layer done
#pragma unroll
        for (int i = 0; i < NPT; ++i)
            if (vid[i] >= 0) cur[vid[i]] = newc[i];
        __syncthreads();                 // state advanced
    }
    // write upd slice: updg[s][node][2] fp32
#pragma unroll
    for (int i = 0; i < NPT; ++i) {
        int v = vid[i];
        if (v >= 0)
            *(f32x2*)(updg + 2 * ((size_t)s * N + v)) = upd[i];
    }
}

// ---- 5. epilogue: h = c*upd + (1-c)*x; out = relu(h @ W^T + b) ----
#define TM 32
#define KC 32
__global__ __launch_bounds__(256) void final_kernel(
        const float* __restrict__ x, const float* __restrict__ updg,
        const float* __restrict__ W, const float* __restrict__ bias,
        const float* __restrict__ wt, float* __restrict__ out, int N) {
    __shared__ float hs[TM * F];
    __shared__ float Wl[KC * 129];
    int tid  = threadIdx.x;
    int row0 = blockIdx.x * TM;
    float cst  = 1.f / (1.f + __expf(-wt[0]));
    float cst1 = 1.f - cst;

    for (int j = tid; j < TM * 32; j += 256) {
        int r = j >> 5, qd = j & 31;
        int gr = row0 + r;
        f32x4 hv = {0.f, 0.f, 0.f, 0.f};
        if (gr < N) {
            f32x4 xv = __builtin_nontemporal_load(&((const f32x4*)(x + (size_t)gr * F))[qd]);
            f32x2 u0 = *(const f32x2*)(updg + 2 * ((size_t)(2 * qd)     * N + gr));
            f32x2 u1 = *(const f32x2*)(updg + 2 * ((size_t)(2 * qd + 1) * N + gr));
            hv.x = cst * u0.x + cst1 * xv.x;
            hv.y = cst * u0.y + cst1 * xv.y;
            hv.z = cst * u1.x + cst1 * xv.z;
            hv.w = cst * u1.y + cst1 * xv.w;
        }
        ((f32x4*)hs)[j] = hv;
    }

    int c  = tid & 127;
    int rg = tid >> 7;
    float acc[16];
#pragma unroll
    for (int i = 0; i < 16; ++i) acc[i] = 0.f;
    for (int kc = 0; kc < F; kc += KC) {
        __syncthreads();
        for (int j = tid; j < KC * F; j += 256) {
            int c2 = j >> 5, kk = j & 31;
            Wl[kk * 129 + c2] = W[(size_t)c2 * F + kc + kk];
        }
        __syncthreads();
#pragma unroll 8
        for (int kk = 0; kk < KC; ++kk) {
            float w = Wl[kk * 129 + c];
#pragma unroll
            for (int r = 0; r < 16; ++r)
                acc[r] += hs[(rg * 16 + r) * F + kc + kk] * w;
        }
    }
    float bv = bias[c];
#pragma unroll
    for (int r = 0; r < 16; ++r) {
        int gr = row0 + rg * 16 + r;
        if (gr < N) {
            float v = acc[r] + bv;
            out[(size_t)gr * F + c] = v > 0.f ? v : 0.f;
        }
    }
}

extern "C" void kernel_launch(void* const* d_in, const int* in_sizes, int n_in,
                              void* d_out, int out_size, void* d_ws, size_t ws_size,
                              hipStream_t stream) {
    const float* x   = (const float*)d_in[0];
    const int*   ei  = (const int*)d_in[1];
    const float* kv  = (const float*)d_in[2];
    const float* wt  = (const float*)d_in[3];
    const float* W   = (const float*)d_in[4];
    const float* b   = (const float*)d_in[5];
    float* out = (float*)d_out;

    const int E = in_sizes[1] / 2;
    const int N = in_sizes[0] / F;
    const int L = in_sizes[2];
    const int* row = ei;           // edge_index[0]
    const int* col = ei + E;       // edge_index[1]
    const size_t NF = (size_t)N * F;
    const int total4 = (int)(NF / 4);

    size_t off = 0;
    auto alloc = [&](size_t bytes) {
        void* p = (char*)d_ws + off;
        off += (bytes + 255) & ~(size_t)255;
        return p;
    };
    int*      hist   = (int*)alloc((size_t)NREP * N * 4);
    int*      cursor = (int*)alloc((size_t)NREP * N * 4);
    int*      startp = (int*)alloc((size_t)(N + 1) * 4);
    float*    dinv   = (float*)alloc((size_t)N * 4);
    int*      norder = (int*)alloc((size_t)N * 4);
    ER8*      edges  = (ER8*)alloc((size_t)E * sizeof(ER8));
    _Float16* xh     = (_Float16*)alloc(NF * 2);
    float*    updg   = (float*)alloc(NF * 4);     // [F/2 slices][N][2] fp32
    (void)ws_size;

    (void)hipMemsetAsync(hist, 0, (size_t)NREP * N * 4, stream);

    const int work = (E > total4 ? E : total4);
    const int nb_edge = (work + 256 * EPT - 1) / (256 * EPT);   // same geometry for bucket
    convdeg_kernel<<<nb_edge, 256, 0, stream>>>(x, xh, total4, col, hist, E, N);
    nodeproc_kernel<<<1, 1024, 0, stream>>>(hist, dinv, startp, cursor, norder, N);
    bucket_kernel<<<nb_edge, 256, 0, stream>>>(row, col, dinv, cursor, edges, E, N);

    prop_kernel<<<F / 2, PB, 0, stream>>>(xh, edges, startp, norder, kv, updg, N, L);

    final_kernel<<<(N + TM - 1) / TM, 256, 0, stream>>>(x, updg, W, b, wt, out, N);
}

// Round 14
// 249.201 us; speedup vs baseline: 2.8201x; 2.8201x over previous
//
#include <hip/hip_runtime.h>
#include <stdint.h>

#define F 128
#define NREP 8          // cursor/histogram replicas (contention /8)
#define EPT 8           // edges per thread in histogram/bucket

// native clang vectors (accepted by __builtin_nontemporal_* and packed math)
typedef float f32x2 __attribute__((ext_vector_type(2)));
typedef float f32x4 __attribute__((ext_vector_type(4)));
typedef _Float16 h2 __attribute__((ext_vector_type(2)));

union H4 { f32x2 f2; h2 p[2]; _Float16 h[4]; };
union HS { _Float16 h; unsigned short u; };
union HP { uint32_t u; h2 p; };

// packed edge record: low16 = src node, high16 = fp16 norm
typedef uint32_t ERec;

// ---- 1. fused: x(fp32)->xh(fp16, [half][node][64] layout) + replicated histogram ----
__global__ void convdeg_kernel(const float* __restrict__ x, _Float16* __restrict__ xh,
                               int total4, const int* __restrict__ col,
                               int* __restrict__ hist, int E, int N) {
    int rep = blockIdx.x & (NREP - 1);
    int i0 = (blockIdx.x * blockDim.x + threadIdx.x) * EPT;
    int* h = hist + (size_t)rep * N;
#pragma unroll
    for (int u = 0; u < EPT; ++u) {
        int e = i0 + u;
        if (e < E) atomicAdd(&h[__builtin_nontemporal_load(&col[e])], 1);
    }
#pragma unroll
    for (int u = 0; u < EPT; ++u) {
        int i = i0 + u;
        if (i < total4) {
            f32x4 v = __builtin_nontemporal_load(&((const f32x4*)x)[i]);
            H4 p;
            p.h[0] = (_Float16)v.x; p.h[1] = (_Float16)v.y;
            p.h[2] = (_Float16)v.z; p.h[3] = (_Float16)v.w;
            int node = i >> 5, q = i & 31;       // q = feature quad 0..31
            int d4 = ((q >> 4) * N + node) * 16 + (q & 15);   // [hf][node][64] as 8B units
            ((f32x2*)xh)[d4] = p.f2;
        }
    }
}

// ---- 2. fused node-side: deg-sum + dinv + exclusive scan + cursor seed ----
__global__ __launch_bounds__(1024) void nodeproc_kernel(
        const int* __restrict__ hist, float* __restrict__ dinv,
        int* __restrict__ start, int* __restrict__ cursor, int N) {
    __shared__ int wsum[16];
    __shared__ int carry_s;
    int tid = threadIdx.x, lane = tid & 63, wid = tid >> 6;
    if (tid == 0) carry_s = 0;
    __syncthreads();
    for (int base = 0; base < N; base += 1024) {
        int i = base + tid;
        int h[NREP];
        int v = 0;
        if (i < N) {
#pragma unroll
            for (int r = 0; r < NREP; ++r) { h[r] = hist[(size_t)r * N + i]; v += h[r]; }
            int d = v < 1 ? 1 : v;
            dinv[i] = rsqrtf((float)d);
        }
        int inc = v;                              // wave-inclusive scan
        for (int off = 1; off < 64; off <<= 1) {
            int t = __shfl_up(inc, off, 64);
            if (lane >= off) inc += t;
        }
        if (lane == 63) wsum[wid] = inc;
        __syncthreads();
        if (wid == 0) {
            int wv = (lane < 16) ? wsum[lane] : 0;
            for (int off = 1; off < 16; off <<= 1) {
                int t = __shfl_up(wv, off, 64);
                if (lane >= off) wv += t;
            }
            if (lane < 16) wsum[lane] = wv;       // inclusive wave totals
        }
        __syncthreads();
        int carry = carry_s;
        int woff = (wid > 0) ? wsum[wid - 1] : 0;
        if (i < N) {
            int st = carry + woff + inc - v;      // exclusive prefix
            start[i] = st;
            int run = st;
#pragma unroll
            for (int r = 0; r < NREP; ++r) { cursor[(size_t)r * N + i] = run; run += h[r]; }
        }
        __syncthreads();
        if (tid == 0) carry_s = carry + wsum[15];
        __syncthreads();
    }
    if (tid == 0) start[N] = carry_s;
}

// ---- 3. bucket scatter: packed 4B records, pre-seeded replicated cursors ----
__global__ void bucket_kernel(const int* __restrict__ row, const int* __restrict__ col,
                              const float* __restrict__ dinv,
                              int* __restrict__ cursor, ERec* __restrict__ edges,
                              int E, int N) {
    int rep = blockIdx.x & (NREP - 1);
    int e0 = (blockIdx.x * blockDim.x + threadIdx.x) * EPT;
    int* cur = cursor + (size_t)rep * N;
    int cs[EPT], rs[EPT], pos[EPT];
    float nm[EPT];
#pragma unroll
    for (int u = 0; u < EPT; ++u) {
        int e = e0 + u;
        if (e < E) {
            cs[u] = __builtin_nontemporal_load(&col[e]);
            rs[u] = __builtin_nontemporal_load(&row[e]);
        }
    }
#pragma unroll
    for (int u = 0; u < EPT; ++u) {
        int e = e0 + u;
        if (e < E) {
            nm[u]  = dinv[rs[u]] * dinv[cs[u]];
            pos[u] = atomicAdd(&cur[cs[u]], 1);
        }
    }
#pragma unroll
    for (int u = 0; u < EPT; ++u) {
        int e = e0 + u;
        if (e < E) {
            HS hs; hs.h = (_Float16)nm[u];
            ERec rec = (uint32_t)rs[u] | ((uint32_t)hs.u << 16);
            edges[pos[u]] = rec;               // reused by layers -> cacheable
        }
    }
}

// ---- 4. one layer, XCD-affine feature halves ----
// blockIdx%8 ~ XCD; XCDs 0-3 process feature half 0, XCDs 4-7 half 1.
// Per-XCD random working set = N*64*2B = 1.28 MB -> L2-resident.
// Wave per (node, half); quarter q handles staged edges j+4u+q; lane li
// covers features 4li..4li+3 of the half (f32x2 = 8B gather/lane).
__global__ __launch_bounds__(256) void layer_kernel(
        const _Float16* __restrict__ cin, _Float16* __restrict__ cout,
        const int* __restrict__ start, const ERec* __restrict__ edges, int N) {
    int B = blockIdx.x;
    int xcd = B & 7, slot = B >> 3;
    int hf  = xcd >> 2;
    int wid = threadIdx.x >> 6, lane = threadIdx.x & 63;
    int node = (slot * 4 + (xcd & 3)) * 4 + wid;
    if (node >= N) return;
    int q  = lane >> 4;        // quarter 0..3
    int li = lane & 15;        // lane-in-quarter
    const _Float16* cbase = cin  + (size_t)hf * N * 64;
    _Float16*       obase = cout + (size_t)hf * N * 64;
    int s = start[node], t = start[node + 1];

    float a[4];
#pragma unroll
    for (int i = 0; i < 4; ++i) a[i] = 0.f;

    for (int base = s; base < t; base += 64) {
        int cnt = t - base; if (cnt > 64) cnt = 64;
        ERec rec = edges[base + (lane < cnt ? lane : cnt - 1)];   // coalesced staging
        int j = 0;
        for (; j + 32 <= cnt; j += 32) {
            h2 hacc[2];
            hacc[0] = (h2)(_Float16)0.f; hacc[1] = (h2)(_Float16)0.f;
#pragma unroll
            for (int u = 0; u < 8; ++u) {          // 8 edges per quarter
                int idx = j + 4 * u + q;
                uint32_t r_ = (uint32_t)__shfl((int)rec, idx, 64);
                int s_ = (int)(r_ & 0xffffu);
                HP n; n.u = (r_ >> 16) * 0x00010001u;   // dup norm in both halves
                H4 v; v.f2 = ((const f32x2*)(cbase + (size_t)s_ * 64))[li];
                hacc[0] += n.p * v.p[0];           // v_pk_fma_f16
                hacc[1] += n.p * v.p[1];
            }
            a[0] += (float)hacc[0][0]; a[1] += (float)hacc[0][1];
            a[2] += (float)hacc[1][0]; a[3] += (float)hacc[1][1];
        }
        for (; j < cnt; j += 4) {                  // remainder: fp32 path
            int idx = j + q;
            int ic  = idx < cnt ? idx : j;
            uint32_t r_ = (uint32_t)__shfl((int)rec, ic, 64);
            int s_ = (int)(r_ & 0xffffu);
            HS hs; hs.u = (unsigned short)(r_ >> 16);
            float n_ = (float)hs.h;
            if (idx >= cnt) n_ = 0.f;
            H4 v; v.f2 = ((const f32x2*)(cbase + (size_t)s_ * 64))[li];
#pragma unroll
            for (int i = 0; i < 4; ++i) a[i] += n_ * (float)v.h[i];
        }
    }
    // combine quarters (lanes li, li+16, li+32, li+48 hold same features)
#pragma unroll
    for (int i = 0; i < 4; ++i) {
        a[i] += __shfl_xor(a[i], 16, 64);
        a[i] += __shfl_xor(a[i], 32, 64);
    }
    if (q == 0) {
        H4 c; c.f2 = ((const f32x2*)(cbase + (size_t)node * 64))[li];
        H4 o;
#pragma unroll
        for (int i = 0; i < 4; ++i) o.h[i] = (_Float16)((float)c.h[i] - a[i]);
        __builtin_nontemporal_store(o.f2, &((f32x2*)(obase + (size_t)node * 64))[li]);
    }
}

// ---- 5. epilogue: update = sum_l tanh(k_l)*cur_l; h = c*upd+(1-c)*x;
//          out = relu(h @ W^T + b).  curh slots are [hf][node][64]. ----
#define TM 32
#define KC 32
__global__ __launch_bounds__(256) void final_kernel(
        const float* __restrict__ x, const _Float16* __restrict__ curh,
        const float* __restrict__ W, const float* __restrict__ bias,
        const float* __restrict__ kv, const float* __restrict__ wt,
        float* __restrict__ out, int N, int L) {
    __shared__ float hs[TM * F];
    __shared__ float Wl[KC * 129];
    int tid  = threadIdx.x;
    int row0 = blockIdx.x * TM;
    float cst  = 1.f / (1.f + __expf(-wt[0]));
    float cst1 = 1.f - cst;
    float t[16];
    for (int l = 0; l < L; ++l) t[l] = tanhf(kv[l]);
    const size_t NF = (size_t)N * F;

    for (int j = tid; j < TM * 32; j += 256) {
        int r = j >> 5, qd = j & 31;
        int gr = row0 + r;
        f32x4 hv = {0.f, 0.f, 0.f, 0.f};
        if (gr < N) {
            f32x4 xv = __builtin_nontemporal_load(&((const f32x4*)(x + (size_t)gr * F))[qd]);
            int d4 = ((qd >> 4) * N + gr) * 16 + (qd & 15);   // [hf][node][64] 8B units
            float sx = 0.f, sy = 0.f, sz = 0.f, sw = 0.f;
            for (int l = 0; l < L; ++l) {
                H4 u;
                u.f2 = __builtin_nontemporal_load(&((const f32x2*)(curh + (size_t)l * NF))[d4]);
                sx += t[l] * (float)u.h[0]; sy += t[l] * (float)u.h[1];
                sz += t[l] * (float)u.h[2]; sw += t[l] * (float)u.h[3];
            }
            hv.x = cst * sx + cst1 * xv.x;
            hv.y = cst * sy + cst1 * xv.y;
            hv.z = cst * sz + cst1 * xv.z;
            hv.w = cst * sw + cst1 * xv.w;
        }
        ((f32x4*)hs)[j] = hv;
    }

    int c  = tid & 127;
    int rg = tid >> 7;
    float acc[16];
#pragma unroll
    for (int i = 0; i < 16; ++i) acc[i] = 0.f;
    for (int kc = 0; kc < F; kc += KC) {
        __syncthreads();
        for (int j = tid; j < KC * F; j += 256) {
            int c2 = j >> 5, kk = j & 31;
            Wl[kk * 129 + c2] = W[(size_t)c2 * F + kc + kk];
        }
        __syncthreads();
#pragma unroll 8
        for (int kk = 0; kk < KC; ++kk) {
            float w = Wl[kk * 129 + c];
#pragma unroll
            for (int r = 0; r < 16; ++r)
                acc[r] += hs[(rg * 16 + r) * F + kc + kk] * w;
        }
    }
    float bv = bias[c];
#pragma unroll
    for (int r = 0; r < 16; ++r) {
        int gr = row0 + rg * 16 + r;
        if (gr < N) {
            float v = acc[r] + bv;
            out[(size_t)gr * F + c] = v > 0.f ? v : 0.f;
        }
    }
}

extern "C" void kernel_launch(void* const* d_in, const int* in_sizes, int n_in,
                              void* d_out, int out_size, void* d_ws, size_t ws_size,
                              hipStream_t stream) {
    const float* x   = (const float*)d_in[0];
    const int*   ei  = (const int*)d_in[1];
    const float* kv  = (const float*)d_in[2];
    const float* wt  = (const float*)d_in[3];
    const float* W   = (const float*)d_in[4];
    const float* b   = (const float*)d_in[5];
    float* out = (float*)d_out;

    const int E = in_sizes[1] / 2;
    const int N = in_sizes[0] / F;
    const int L = in_sizes[2];
    const int* row = ei;           // edge_index[0]
    const int* col = ei + E;       // edge_index[1]
    const size_t NF = (size_t)N * F;
    const int total4 = (int)(NF / 4);

    size_t off = 0;
    auto alloc = [&](size_t bytes) {
        void* p = (char*)d_ws + off;
        off += (bytes + 255) & ~(size_t)255;
        return p;
    };
    int*      hist   = (int*)alloc((size_t)NREP * N * 4);
    int*      cursor = (int*)alloc((size_t)NREP * N * 4);
    int*      startp = (int*)alloc((size_t)(N + 1) * 4);
    float*    dinv   = (float*)alloc((size_t)N * 4);
    ERec*     edges  = (ERec*)alloc((size_t)E * sizeof(ERec));
    _Float16* xh     = (_Float16*)alloc(NF * 2);
    _Float16* curh   = (_Float16*)alloc((size_t)L * NF * 2);
    (void)ws_size;

    (void)hipMemsetAsync(hist, 0, (size_t)NREP * N * 4, stream);

    const int work = (E > total4 ? E : total4);
    const int nb_edge = (work + 256 * EPT - 1) / (256 * EPT);   // same geometry for bucket
    convdeg_kernel<<<nb_edge, 256, 0, stream>>>(x, xh, total4, col, hist, E, N);
    nodeproc_kernel<<<1, 1024, 0, stream>>>(hist, dinv, startp, cursor, N);
    bucket_kernel<<<nb_edge, 256, 0, stream>>>(row, col, dinv, cursor, edges, E, N);

    const int slots = (N + 15) / 16;           // 4 nodes/block, 4 blocks/half-XCD-group
    const int prop_grid = slots * 8;
    for (int l = 0; l < L; ++l) {
        const _Float16* cin = (l == 0) ? xh : curh + (size_t)(l - 1) * NF;
        _Float16* cout = curh + (size_t)l * NF;
        layer_kernel<<<prop_grid, 256, 0, stream>>>(cin, cout, startp, edges, N);
    }

    final_kernel<<<(N + TM - 1) / TM, 256, 0, stream>>>(x, curh, W, b, kv, wt, out, N, L);
}

// Round 15
// 229.736 us; speedup vs baseline: 3.0590x; 1.0847x over previous
//
#include <hip/hip_runtime.h>
#include <stdint.h>

#define F 128
#define NREP 8          // cursor/histogram replicas (contention /8)
#define EPT 4           // edges per thread in histogram/bucket (r5-r7 proven)

// native clang vectors (accepted by __builtin_nontemporal_* and packed math)
typedef float f32x2 __attribute__((ext_vector_type(2)));
typedef float f32x4 __attribute__((ext_vector_type(4)));
typedef _Float16 h2 __attribute__((ext_vector_type(2)));

union H4 { f32x2 f2; _Float16 h[4]; };
union H8 { f32x4 f4; h2 p[4]; _Float16 h[8]; };
union HS { _Float16 h; unsigned short u; };
union HP { uint32_t u; h2 p; };

// packed edge record: low16 = src node, high16 = fp16 norm
typedef uint32_t ERec;

// ---- 1. fused: x(fp32)->xh(fp16) + replicated in-degree histogram ----
__global__ void convdeg_kernel(const float* __restrict__ x, _Float16* __restrict__ xh,
                               int total4, const int* __restrict__ col,
                               int* __restrict__ hist, int E, int N) {
    int rep = blockIdx.x & (NREP - 1);
    int i0 = (blockIdx.x * blockDim.x + threadIdx.x) * EPT;
    int* h = hist + (size_t)rep * N;
#pragma unroll
    for (int u = 0; u < EPT; ++u) {
        int e = i0 + u;
        if (e < E) atomicAdd(&h[__builtin_nontemporal_load(&col[e])], 1);
    }
#pragma unroll
    for (int u = 0; u < EPT; ++u) {
        int i = i0 + u;
        if (i < total4) {
            f32x4 v = __builtin_nontemporal_load(&((const f32x4*)x)[i]);
            H4 p;
            p.h[0] = (_Float16)v.x; p.h[1] = (_Float16)v.y;
            p.h[2] = (_Float16)v.z; p.h[3] = (_Float16)v.w;
            ((f32x2*)xh)[i] = p.f2;            // reused by layer 0 -> keep cacheable
        }
    }
}

// ---- 2. fused node-side: deg-sum + dinv + exclusive scan + cursor seed ----
__global__ __launch_bounds__(1024) void nodeproc_kernel(
        const int* __restrict__ hist, float* __restrict__ dinv,
        int* __restrict__ start, int* __restrict__ cursor, int N) {
    __shared__ int wsum[16];
    __shared__ int carry_s;
    int tid = threadIdx.x, lane = tid & 63, wid = tid >> 6;
    if (tid == 0) carry_s = 0;
    __syncthreads();
    for (int base = 0; base < N; base += 1024) {
        int i = base + tid;
        int h[NREP];
        int v = 0;
        if (i < N) {
#pragma unroll
            for (int r = 0; r < NREP; ++r) { h[r] = hist[(size_t)r * N + i]; v += h[r]; }
            int d = v < 1 ? 1 : v;
            dinv[i] = rsqrtf((float)d);
        }
        int inc = v;                              // wave-inclusive scan
        for (int off = 1; off < 64; off <<= 1) {
            int t = __shfl_up(inc, off, 64);
            if (lane >= off) inc += t;
        }
        if (lane == 63) wsum[wid] = inc;
        __syncthreads();
        if (wid == 0) {
            int wv = (lane < 16) ? wsum[lane] : 0;
            for (int off = 1; off < 16; off <<= 1) {
                int t = __shfl_up(wv, off, 64);
                if (lane >= off) wv += t;
            }
            if (lane < 16) wsum[lane] = wv;       // inclusive wave totals
        }
        __syncthreads();
        int carry = carry_s;
        int woff = (wid > 0) ? wsum[wid - 1] : 0;
        if (i < N) {
            int st = carry + woff + inc - v;      // exclusive prefix
            start[i] = st;
            int run = st;
#pragma unroll
            for (int r = 0; r < NREP; ++r) { cursor[(size_t)r * N + i] = run; run += h[r]; }
        }
        __syncthreads();
        if (tid == 0) carry_s = carry + wsum[15];
        __syncthreads();
    }
    if (tid == 0) start[N] = carry_s;
}

// ---- 3. bucket scatter: packed 4B records, pre-seeded replicated cursors ----
__global__ void bucket_kernel(const int* __restrict__ row, const int* __restrict__ col,
                              const float* __restrict__ dinv,
                              int* __restrict__ cursor, ERec* __restrict__ edges,
                              int E, int N) {
    int rep = blockIdx.x & (NREP - 1);
    int e0 = (blockIdx.x * blockDim.x + threadIdx.x) * EPT;
    int* cur = cursor + (size_t)rep * N;
    int cs[EPT], rs[EPT], pos[EPT];
    float nm[EPT];
#pragma unroll
    for (int u = 0; u < EPT; ++u) {
        int e = e0 + u;
        if (e < E) {
            cs[u] = __builtin_nontemporal_load(&col[e]);
            rs[u] = __builtin_nontemporal_load(&row[e]);
        }
    }
#pragma unroll
    for (int u = 0; u < EPT; ++u) {
        int e = e0 + u;
        if (e < E) {
            nm[u]  = dinv[rs[u]] * dinv[cs[u]];
            pos[u] = atomicAdd(&cur[cs[u]], 1);
        }
    }
#pragma unroll
    for (int u = 0; u < EPT; ++u) {
        int e = e0 + u;
        if (e < E) {
            HS hs; hs.h = (_Float16)nm[u];
            ERec rec = (uint32_t)rs[u] | ((uint32_t)hs.u << 16);
            edges[pos[u]] = rec;               // reused 8x by layers -> cacheable
        }
    }
}

// ---- 4. one layer: predicated two-phase pipelined gather ----
// Quarter q, lane li covers halves 8*li..8*li+7 (f32x4 = 16B/lane, 256B row).
// Per 32-edge phase: 8 shfl broadcasts, then 8 INDEPENDENT back-to-back loads
// (no fma interleaved -> compiler can't serialize on vmcnt), then 32 pk_fma.
// Out-of-range lanes clamp to edge cnt-1 (one hot line) with norm zeroed.
__global__ __launch_bounds__(256) void layer_kernel(
        const _Float16* __restrict__ cin, _Float16* __restrict__ cout,
        const int* __restrict__ start, const ERec* __restrict__ edges, int N) {
    int node = (blockIdx.x * blockDim.x + threadIdx.x) >> 6;
    int lane = threadIdx.x & 63;
    if (node >= N) return;
    int q  = lane >> 4;        // quarter 0..3
    int li = lane & 15;        // lane-in-quarter
    int s = start[node], t = start[node + 1];

    float a[8];
#pragma unroll
    for (int i = 0; i < 8; ++i) a[i] = 0.f;

    for (int base = s; base < t; base += 64) {
        int cnt = t - base; if (cnt > 64) cnt = 64;
        ERec rec = edges[base + (lane < cnt ? lane : cnt - 1)];   // coalesced staging
#pragma unroll
        for (int ph = 0; ph < 2; ++ph) {
            int j0 = ph * 32;
            if (j0 < cnt) {                    // wave-uniform predicate
                uint32_t rr[8];
#pragma unroll
                for (int u = 0; u < 8; ++u) {  // broadcast 8 records first
                    int idx = j0 + 4 * u + q;
                    int ic  = idx < cnt ? idx : cnt - 1;
                    uint32_t r_ = (uint32_t)__shfl((int)rec, ic, 64);
                    if (idx >= cnt) r_ &= 0xffffu;   // zero norm -> fma adds 0
                    rr[u] = r_;
                }
                H8 v[8];
#pragma unroll
                for (int u = 0; u < 8; ++u)    // 8 independent loads, no fma between
                    v[u].f4 = ((const f32x4*)(cin + (size_t)(rr[u] & 0xffffu) * F))[li];
                h2 hacc[4];
#pragma unroll
                for (int c = 0; c < 4; ++c) hacc[c] = (h2)(_Float16)0.f;
#pragma unroll
                for (int u = 0; u < 8; ++u) {
                    HP n; n.u = (rr[u] >> 16) * 0x00010001u;   // dup norm both halves
#pragma unroll
                    for (int c = 0; c < 4; ++c) hacc[c] += n.p * v[u].p[c];  // pk_fma
                }
#pragma unroll
                for (int c = 0; c < 4; ++c) {  // flush to fp32 every 8 edges (r12 numerics)
                    a[2 * c]     += (float)hacc[c][0];
                    a[2 * c + 1] += (float)hacc[c][1];
                }
            }
        }
    }
    // combine quarters (lanes li, li+16, li+32, li+48 hold same columns)
#pragma unroll
    for (int i = 0; i < 8; ++i) {
        a[i] += __shfl_xor(a[i], 16, 64);
        a[i] += __shfl_xor(a[i], 32, 64);
    }
    if (q == 0) {
        H8 c; c.f4 = ((const f32x4*)(cin + (size_t)node * F))[li];
        H8 o;
#pragma unroll
        for (int i = 0; i < 8; ++i) o.h[i] = (_Float16)((float)c.h[i] - a[i]);
        __builtin_nontemporal_store(o.f4, &((f32x4*)(cout + (size_t)node * F))[li]);
    }
}

// ---- 5. epilogue: update = sum_l tanh(k_l)*cur_l; h = c*upd+(1-c)*x;
//          out = relu(h @ W^T + b) ----
#define TM 32
#define KC 32
__global__ __launch_bounds__(256) void final_kernel(
        const float* __restrict__ x, const _Float16* __restrict__ curh,
        const float* __restrict__ W, const float* __restrict__ bias,
        const float* __restrict__ kv, const float* __restrict__ wt,
        float* __restrict__ out, int N, int L) {
    __shared__ float hs[TM * F];
    __shared__ float Wl[KC * 129];
    int tid  = threadIdx.x;
    int row0 = blockIdx.x * TM;
    float cst  = 1.f / (1.f + __expf(-wt[0]));
    float cst1 = 1.f - cst;
    float t[16];
    for (int l = 0; l < L; ++l) t[l] = tanhf(kv[l]);
    const size_t NF = (size_t)N * F;

    for (int j = tid; j < TM * 32; j += 256) {
        int r = j >> 5, qd = j & 31;
        int gr = row0 + r;
        f32x4 hv = {0.f, 0.f, 0.f, 0.f};
        if (gr < N) {
            f32x4 xv = __builtin_nontemporal_load(&((const f32x4*)(x + (size_t)gr * F))[qd]);
            float sx = 0.f, sy = 0.f, sz = 0.f, sw = 0.f;
            for (int l = 0; l < L; ++l) {
                H4 u;
                u.f2 = __builtin_nontemporal_load(
                    &((const f32x2*)(curh + (size_t)l * NF + (size_t)gr * F))[qd]);
                sx += t[l] * (float)u.h[0]; sy += t[l] * (float)u.h[1];
                sz += t[l] * (float)u.h[2]; sw += t[l] * (float)u.h[3];
            }
            hv.x = cst * sx + cst1 * xv.x;
            hv.y = cst * sy + cst1 * xv.y;
            hv.z = cst * sz + cst1 * xv.z;
            hv.w = cst * sw + cst1 * xv.w;
        }
        ((f32x4*)hs)[j] = hv;
    }

    int c  = tid & 127;
    int rg = tid >> 7;
    float acc[16];
#pragma unroll
    for (int i = 0; i < 16; ++i) acc[i] = 0.f;
    for (int kc = 0; kc < F; kc += KC) {
        __syncthreads();
        for (int j = tid; j < KC * F; j += 256) {
            int c2 = j >> 5, kk = j & 31;
            Wl[kk * 129 + c2] = W[(size_t)c2 * F + kc + kk];
        }
        __syncthreads();
#pragma unroll 8
        for (int kk = 0; kk < KC; ++kk) {
            float w = Wl[kk * 129 + c];
#pragma unroll
            for (int r = 0; r < 16; ++r)
                acc[r] += hs[(rg * 16 + r) * F + kc + kk] * w;
        }
    }
    float bv = bias[c];
#pragma unroll
    for (int r = 0; r < 16; ++r) {
        int gr = row0 + rg * 16 + r;
        if (gr < N) {
            float v = acc[r] + bv;
            out[(size_t)gr * F + c] = v > 0.f ? v : 0.f;
        }
    }
}

extern "C" void kernel_launch(void* const* d_in, const int* in_sizes, int n_in,
                              void* d_out, int out_size, void* d_ws, size_t ws_size,
                              hipStream_t stream) {
    const float* x   = (const float*)d_in[0];
    const int*   ei  = (const int*)d_in[1];
    const float* kv  = (const float*)d_in[2];
    const float* wt  = (const float*)d_in[3];
    const float* W   = (const float*)d_in[4];
    const float* b   = (const float*)d_in[5];
    float* out = (float*)d_out;

    const int E = in_sizes[1] / 2;
    const int N = in_sizes[0] / F;
    const int L = in_sizes[2];
    const int* row = ei;           // edge_index[0]
    const int* col = ei + E;       // edge_index[1]
    const size_t NF = (size_t)N * F;
    const int total4 = (int)(NF / 4);

    size_t off = 0;
    auto alloc = [&](size_t bytes) {
        void* p = (char*)d_ws + off;
        off += (bytes + 255) & ~(size_t)255;
        return p;
    };
    int*      hist   = (int*)alloc((size_t)NREP * N * 4);
    int*      cursor = (int*)alloc((size_t)NREP * N * 4);
    int*      startp = (int*)alloc((size_t)(N + 1) * 4);
    float*    dinv   = (float*)alloc((size_t)N * 4);
    ERec*     edges  = (ERec*)alloc((size_t)E * sizeof(ERec));
    _Float16* xh     = (_Float16*)alloc(NF * 2);
    _Float16* curh   = (_Float16*)alloc((size_t)L * NF * 2);
    (void)ws_size;

    (void)hipMemsetAsync(hist, 0, (size_t)NREP * N * 4, stream);

    const int work = (E > total4 ? E : total4);
    const int nb_edge = (work + 256 * EPT - 1) / (256 * EPT);   // same geometry for bucket
    convdeg_kernel<<<nb_edge, 256, 0, stream>>>(x, xh, total4, col, hist, E, N);
    nodeproc_kernel<<<1, 1024, 0, stream>>>(hist, dinv, startp, cursor, N);
    bucket_kernel<<<nb_edge, 256, 0, stream>>>(row, col, dinv, cursor, edges, E, N);

    for (int l = 0; l < L; ++l) {
        const _Float16* cin = (l == 0) ? xh : curh + (size_t)(l - 1) * NF;
        _Float16* cout = curh + (size_t)l * NF;
        layer_kernel<<<(N * 64 + 255) / 256, 256, 0, stream>>>(cin, cout, startp, edges, N);
    }

    final_kernel<<<(N + TM - 1) / TM, 256, 0, stream>>>(x, curh, W, b, kv, wt, out, N, L);
}

// Round 16
// 224.495 us; speedup vs baseline: 3.1305x; 1.0233x over previous
//
#include <hip/hip_runtime.h>
#include <stdint.h>

#define F 128
#define NREP 8          // cursor/histogram replicas (contention /8)
#define EPT 4           // edges per thread in histogram/bucket (r5-r7 proven)

// native clang vectors (accepted by __builtin_nontemporal_* and packed math)
typedef float f32x2 __attribute__((ext_vector_type(2)));
typedef float f32x4 __attribute__((ext_vector_type(4)));
typedef _Float16 h2 __attribute__((ext_vector_type(2)));

union H4 { f32x2 f2; _Float16 h[4]; };
union H8 { f32x4 f4; h2 p[4]; _Float16 h[8]; };
union HS { _Float16 h; unsigned short u; };
union HP { uint32_t u; h2 p; };

// packed edge record: low16 = src node, high16 = fp16 norm
typedef uint32_t ERec;

// ---- 1. fused: x(fp32)->xh(fp16) + replicated in-degree histogram ----
__global__ void convdeg_kernel(const float* __restrict__ x, _Float16* __restrict__ xh,
                               int total4, const int* __restrict__ col,
                               int* __restrict__ hist, int E, int N) {
    int rep = blockIdx.x & (NREP - 1);
    int i0 = (blockIdx.x * blockDim.x + threadIdx.x) * EPT;
    int* h = hist + (size_t)rep * N;
#pragma unroll
    for (int u = 0; u < EPT; ++u) {
        int e = i0 + u;
        if (e < E) atomicAdd(&h[__builtin_nontemporal_load(&col[e])], 1);
    }
#pragma unroll
    for (int u = 0; u < EPT; ++u) {
        int i = i0 + u;
        if (i < total4) {
            f32x4 v = __builtin_nontemporal_load(&((const f32x4*)x)[i]);
            H4 p;
            p.h[0] = (_Float16)v.x; p.h[1] = (_Float16)v.y;
            p.h[2] = (_Float16)v.z; p.h[3] = (_Float16)v.w;
            ((f32x2*)xh)[i] = p.f2;            // reused by layer 0 -> keep cacheable
        }
    }
}

// ---- 2a. parallel: degc = sum over replicas; dinv = rsqrt(max(deg,1)) ----
__global__ void sumdinv_kernel(const int* __restrict__ hist, int* __restrict__ degc,
                               float* __restrict__ dinv, int N) {
    int n = blockIdx.x * blockDim.x + threadIdx.x;
    if (n < N) {
        int d = 0;
#pragma unroll
        for (int r = 0; r < NREP; ++r) d += hist[(size_t)r * N + n];
        degc[n] = d;
        if (d < 1) d = 1;
        dinv[n] = rsqrtf((float)d);
    }
}

// ---- 2b. single-block scan over degc only (80 KB total traffic) ----
__global__ __launch_bounds__(1024) void scan_kernel(const int* __restrict__ degc,
                                                    int* __restrict__ start, int N) {
    __shared__ int wsum[16];
    __shared__ int carry_s;
    int tid = threadIdx.x, lane = tid & 63, wid = tid >> 6;
    if (tid == 0) carry_s = 0;
    __syncthreads();
    for (int base = 0; base < N; base += 1024) {
        int i = base + tid;
        int v = (i < N) ? degc[i] : 0;
        int inc = v;                              // wave-inclusive scan
        for (int off = 1; off < 64; off <<= 1) {
            int t = __shfl_up(inc, off, 64);
            if (lane >= off) inc += t;
        }
        if (lane == 63) wsum[wid] = inc;
        __syncthreads();
        if (wid == 0) {
            int wv = (lane < 16) ? wsum[lane] : 0;
            for (int off = 1; off < 16; off <<= 1) {
                int t = __shfl_up(wv, off, 64);
                if (lane >= off) wv += t;
            }
            if (lane < 16) wsum[lane] = wv;       // inclusive wave totals
        }
        __syncthreads();
        int carry = carry_s;
        int woff = (wid > 0) ? wsum[wid - 1] : 0;
        if (i < N) start[i] = carry + woff + inc - v;   // exclusive
        __syncthreads();
        if (tid == 0) carry_s = carry + wsum[15];
        __syncthreads();
    }
    if (tid == 0) start[N] = carry_s;
}

// ---- 2c. parallel: seed cursor[r][c] = start[c] + prefix_r(hist[.][c]) ----
__global__ void seed_kernel(const int* __restrict__ hist, const int* __restrict__ start,
                            int* __restrict__ cursor, int N) {
    int n = blockIdx.x * blockDim.x + threadIdx.x;
    if (n < N) {
        int run = start[n];
#pragma unroll
        for (int r = 0; r < NREP; ++r) {
            cursor[(size_t)r * N + n] = run;
            run += hist[(size_t)r * N + n];
        }
    }
}

// ---- 3. bucket scatter: packed 4B records, pre-seeded replicated cursors ----
__global__ void bucket_kernel(const int* __restrict__ row, const int* __restrict__ col,
                              const float* __restrict__ dinv,
                              int* __restrict__ cursor, ERec* __restrict__ edges,
                              int E, int N) {
    int rep = blockIdx.x & (NREP - 1);
    int e0 = (blockIdx.x * blockDim.x + threadIdx.x) * EPT;
    int* cur = cursor + (size_t)rep * N;
    int cs[EPT], rs[EPT], pos[EPT];
    float nm[EPT];
#pragma unroll
    for (int u = 0; u < EPT; ++u) {
        int e = e0 + u;
        if (e < E) {
            cs[u] = __builtin_nontemporal_load(&col[e]);
            rs[u] = __builtin_nontemporal_load(&row[e]);
        }
    }
#pragma unroll
    for (int u = 0; u < EPT; ++u) {
        int e = e0 + u;
        if (e < E) {
            nm[u]  = dinv[rs[u]] * dinv[cs[u]];
            pos[u] = atomicAdd(&cur[cs[u]], 1);
        }
    }
#pragma unroll
    for (int u = 0; u < EPT; ++u) {
        int e = e0 + u;
        if (e < E) {
            HS hs; hs.h = (_Float16)nm[u];
            ERec rec = (uint32_t)rs[u] | ((uint32_t)hs.u << 16);
            edges[pos[u]] = rec;               // reused 8x by layers -> cacheable
        }
    }
}

// ---- 4. one layer: predicated two-phase pipelined gather (r15 proven) ----
__global__ __launch_bounds__(256) void layer_kernel(
        const _Float16* __restrict__ cin, _Float16* __restrict__ cout,
        const int* __restrict__ start, const ERec* __restrict__ edges, int N) {
    int node = (blockIdx.x * blockDim.x + threadIdx.x) >> 6;
    int lane = threadIdx.x & 63;
    if (node >= N) return;
    int q  = lane >> 4;        // quarter 0..3
    int li = lane & 15;        // lane-in-quarter
    int s = start[node], t = start[node + 1];

    float a[8];
#pragma unroll
    for (int i = 0; i < 8; ++i) a[i] = 0.f;

    for (int base = s; base < t; base += 64) {
        int cnt = t - base; if (cnt > 64) cnt = 64;
        ERec rec = edges[base + (lane < cnt ? lane : cnt - 1)];   // coalesced staging
#pragma unroll
        for (int ph = 0; ph < 2; ++ph) {
            int j0 = ph * 32;
            if (j0 < cnt) {                    // wave-uniform predicate
                uint32_t rr[8];
#pragma unroll
                for (int u = 0; u < 8; ++u) {  // broadcast 8 records first
                    int idx = j0 + 4 * u + q;
                    int ic  = idx < cnt ? idx : cnt - 1;
                    uint32_t r_ = (uint32_t)__shfl((int)rec, ic, 64);
                    if (idx >= cnt) r_ &= 0xffffu;   // zero norm -> fma adds 0
                    rr[u] = r_;
                }
                H8 v[8];
#pragma unroll
                for (int u = 0; u < 8; ++u)    // 8 independent loads, no fma between
                    v[u].f4 = ((const f32x4*)(cin + (size_t)(rr[u] & 0xffffu) * F))[li];
                h2 hacc[4];
#pragma unroll
                for (int c = 0; c < 4; ++c) hacc[c] = (h2)(_Float16)0.f;
#pragma unroll
                for (int u = 0; u < 8; ++u) {
                    HP n; n.u = (rr[u] >> 16) * 0x00010001u;   // dup norm both halves
#pragma unroll
                    for (int c = 0; c < 4; ++c) hacc[c] += n.p * v[u].p[c];  // pk_fma
                }
#pragma unroll
                for (int c = 0; c < 4; ++c) {  // flush to fp32 every 8 edges
                    a[2 * c]     += (float)hacc[c][0];
                    a[2 * c + 1] += (float)hacc[c][1];
                }
            }
        }
    }
    // combine quarters (lanes li, li+16, li+32, li+48 hold same columns)
#pragma unroll
    for (int i = 0; i < 8; ++i) {
        a[i] += __shfl_xor(a[i], 16, 64);
        a[i] += __shfl_xor(a[i], 32, 64);
    }
    if (q == 0) {
        H8 c; c.f4 = ((const f32x4*)(cin + (size_t)node * F))[li];
        H8 o;
#pragma unroll
        for (int i = 0; i < 8; ++i) o.h[i] = (_Float16)((float)c.h[i] - a[i]);
        __builtin_nontemporal_store(o.f4, &((f32x4*)(cout + (size_t)node * F))[li]);
    }
}

// ---- 5. epilogue: update = sum_l tanh(k_l)*cur_l; h = c*upd+(1-c)*x;
//          out = relu(h @ W^T + b) ----
#define TM 32
#define KC 32
__global__ __launch_bounds__(256) void final_kernel(
        const float* __restrict__ x, const _Float16* __restrict__ curh,
        const float* __restrict__ W, const float* __restrict__ bias,
        const float* __restrict__ kv, const float* __restrict__ wt,
        float* __restrict__ out, int N, int L) {
    __shared__ float hs[TM * F];
    __shared__ float Wl[KC * 129];
    int tid  = threadIdx.x;
    int row0 = blockIdx.x * TM;
    float cst  = 1.f / (1.f + __expf(-wt[0]));
    float cst1 = 1.f - cst;
    float t[16];
    for (int l = 0; l < L; ++l) t[l] = tanhf(kv[l]);
    const size_t NF = (size_t)N * F;

    for (int j = tid; j < TM * 32; j += 256) {
        int r = j >> 5, qd = j & 31;
        int gr = row0 + r;
        f32x4 hv = {0.f, 0.f, 0.f, 0.f};
        if (gr < N) {
            f32x4 xv = __builtin_nontemporal_load(&((const f32x4*)(x + (size_t)gr * F))[qd]);
            float sx = 0.f, sy = 0.f, sz = 0.f, sw = 0.f;
            for (int l = 0; l < L; ++l) {
                H4 u;
                u.f2 = __builtin_nontemporal_load(
                    &((const f32x2*)(curh + (size_t)l * NF + (size_t)gr * F))[qd]);
                sx += t[l] * (float)u.h[0]; sy += t[l] * (float)u.h[1];
                sz += t[l] * (float)u.h[2]; sw += t[l] * (float)u.h[3];
            }
            hv.x = cst * sx + cst1 * xv.x;
            hv.y = cst * sy + cst1 * xv.y;
            hv.z = cst * sz + cst1 * xv.z;
            hv.w = cst * sw + cst1 * xv.w;
        }
        ((f32x4*)hs)[j] = hv;
    }

    int c  = tid & 127;
    int rg = tid >> 7;
    float acc[16];
#pragma unroll
    for (int i = 0; i < 16; ++i) acc[i] = 0.f;
    for (int kc = 0; kc < F; kc += KC) {
        __syncthreads();
        for (int j = tid; j < KC * F; j += 256) {
            int c2 = j >> 5, kk = j & 31;
            Wl[kk * 129 + c2] = W[(size_t)c2 * F + kc + kk];
        }
        __syncthreads();
#pragma unroll 8
        for (int kk = 0; kk < KC; ++kk) {
            float w = Wl[kk * 129 + c];
#pragma unroll
            for (int r = 0; r < 16; ++r)
                acc[r] += hs[(rg * 16 + r) * F + kc + kk] * w;
        }
    }
    float bv = bias[c];
#pragma unroll
    for (int r = 0; r < 16; ++r) {
        int gr = row0 + rg * 16 + r;
        if (gr < N) {
            float v = acc[r] + bv;
            out[(size_t)gr * F + c] = v > 0.f ? v : 0.f;
        }
    }
}

extern "C" void kernel_launch(void* const* d_in, const int* in_sizes, int n_in,
                              void* d_out, int out_size, void* d_ws, size_t ws_size,
                              hipStream_t stream) {
    const float* x   = (const float*)d_in[0];
    const int*   ei  = (const int*)d_in[1];
    const float* kv  = (const float*)d_in[2];
    const float* wt  = (const float*)d_in[3];
    const float* W   = (const float*)d_in[4];
    const float* b   = (const float*)d_in[5];
    float* out = (float*)d_out;

    const int E = in_sizes[1] / 2;
    const int N = in_sizes[0] / F;
    const int L = in_sizes[2];
    const int* row = ei;           // edge_index[0]
    const int* col = ei + E;       // edge_index[1]
    const size_t NF = (size_t)N * F;
    const int total4 = (int)(NF / 4);

    size_t off = 0;
    auto alloc = [&](size_t bytes) {
        void* p = (char*)d_ws + off;
        off += (bytes + 255) & ~(size_t)255;
        return p;
    };
    int*      hist   = (int*)alloc((size_t)NREP * N * 4);
    int*      cursor = (int*)alloc((size_t)NREP * N * 4);
    int*      degc   = (int*)alloc((size_t)N * 4);
    int*      startp = (int*)alloc((size_t)(N + 1) * 4);
    float*    dinv   = (float*)alloc((size_t)N * 4);
    ERec*     edges  = (ERec*)alloc((size_t)E * sizeof(ERec));
    _Float16* xh     = (_Float16*)alloc(NF * 2);
    _Float16* curh   = (_Float16*)alloc((size_t)L * NF * 2);
    (void)ws_size;

    (void)hipMemsetAsync(hist, 0, (size_t)NREP * N * 4, stream);

    const int work = (E > total4 ? E : total4);
    const int nb_edge = (work + 256 * EPT - 1) / (256 * EPT);   // same geometry for bucket
    convdeg_kernel<<<nb_edge, 256, 0, stream>>>(x, xh, total4, col, hist, E, N);
    sumdinv_kernel<<<(N + 255) / 256, 256, 0, stream>>>(hist, degc, dinv, N);
    scan_kernel<<<1, 1024, 0, stream>>>(degc, startp, N);
    seed_kernel<<<(N + 255) / 256, 256, 0, stream>>>(hist, startp, cursor, N);
    bucket_kernel<<<nb_edge, 256, 0, stream>>>(row, col, dinv, cursor, edges, E, N);

    for (int l = 0; l < L; ++l) {
        const _Float16* cin = (l == 0) ? xh : curh + (size_t)(l - 1) * NF;
        _Float16* cout = curh + (size_t)l * NF;
        layer_kernel<<<(N * 64 + 255) / 256, 256, 0, stream>>>(cin, cout, startp, edges, N);
    }

    final_kernel<<<(N + TM - 1) / TM, 256, 0, stream>>>(x, curh, W, b, kv, wt, out, N, L);
}